// Round 3
// baseline (181.633 us; speedup 1.0000x reference)
//
#include <hip/hip_runtime.h>
#include <hip/hip_bf16.h>

// NT-Xent loss, 2B=8192, D=128, T=0.5.
// sim = (N N^T) * 2 with N = row-normalized embeddings (bf16, MFMA).
// Per-row sum of exp(sim-2) over ALL columns (fixed max=2 since cos<=1);
// the j==i and j==i^4096 (positive-pair) terms are subtracted afterwards
// in k_aux from fp32 dots of the same bf16 data. picked logit in fp32.

typedef __bf16 bf16x8 __attribute__((ext_vector_type(8)));
typedef float floatx4 __attribute__((ext_vector_type(4)));

#define TWO_B 8192
#define B_HALF 4096
#define D 128
#define INV_T 2.0f                 // 1/temperature
#define FIXED_MAX 2.0f             // logit upper bound (cos<=1)
#define C_EXP 2.885390081777927f   // INV_T * log2(e) == FIXED_MAX * log2(e)

#if defined(__has_builtin) && __has_builtin(__builtin_amdgcn_exp2f)
#define EXP2F(x) __builtin_amdgcn_exp2f(x)   // raw v_exp_f32; arg in [-5.8, 0]
#else
#define EXP2F(x) exp2f(x)
#endif

// -------- kernel 1: normalize rows -> bf16; zero l_arr/accum/counter -----
__global__ void k_normalize(const float* __restrict__ emb,
                            __bf16* __restrict__ nb,
                            float* __restrict__ l_arr,
                            float* __restrict__ accum,
                            unsigned int* __restrict__ counter) {
    int wv   = threadIdx.x >> 6;
    int lane = threadIdx.x & 63;
    int row  = blockIdx.x * 4 + wv;
    const float2* e2 = reinterpret_cast<const float2*>(emb + (size_t)row * D);
    float2 v = e2[lane];
    float ss = v.x * v.x + v.y * v.y;
#pragma unroll
    for (int off = 32; off >= 1; off >>= 1) ss += __shfl_xor(ss, off, 64);
    float rn = rsqrtf(fmaxf(ss, 1e-16f));
    union { __bf16 h[2]; unsigned int u; } pk;
    pk.h[0] = (__bf16)(v.x * rn);
    pk.h[1] = (__bf16)(v.y * rn);
    reinterpret_cast<unsigned int*>(nb)[row * 64 + lane] = pk.u;
    if (blockIdx.x < TWO_B / 256) l_arr[blockIdx.x * 256 + threadIdx.x] = 0.f;
    if (blockIdx.x == 0 && threadIdx.x == 0) { accum[0] = 0.f; counter[0] = 0u; }
}

// ------- kernel 2: fused Gram-matrix MFMA + unmasked exp-sum per row -----
// grid: (8192/128 row-blocks, 32 col-splits) = 2048 blocks (8/CU),
// block: 256 (4 waves x 32 rows); each block covers 128 rows x 256 cols.
__global__ __launch_bounds__(256, 4) void k_simlse(const __bf16* __restrict__ nb,
                                                   float* __restrict__ l_arr) {
    const int lane = threadIdx.x & 63;
    const int w    = threadIdx.x >> 6;
    const int m    = lane & 15;
    const int quad = lane >> 4;
    const int row0 = blockIdx.x * 128 + w * 32;   // this wave: rows row0..row0+31
    const int col0 = blockIdx.y * 256;            // this block: 256 columns

    // A fragments: two 16-row tiles, full K=128, kept in registers (32 VGPR)
    bf16x8 a0[4], a1[4];
#pragma unroll
    for (int kc = 0; kc < 4; ++kc) {
        a0[kc] = *reinterpret_cast<const bf16x8*>(
            nb + (size_t)(row0 + m) * D + kc * 32 + quad * 8);
        a1[kc] = *reinterpret_cast<const bf16x8*>(
            nb + (size_t)(row0 + 16 + m) * D + kc * 32 + quad * 8);
    }

    float l0[4] = {0.f, 0.f, 0.f, 0.f};
    float l1[4] = {0.f, 0.f, 0.f, 0.f};

    auto loadB = [&](bf16x8* buf, int sub) {
        const __bf16* bp = nb + (size_t)(col0 + sub * 16 + m) * D + quad * 8;
        buf[0] = *reinterpret_cast<const bf16x8*>(bp);
        buf[1] = *reinterpret_cast<const bf16x8*>(bp + 32);
        buf[2] = *reinterpret_cast<const bf16x8*>(bp + 64);
        buf[3] = *reinterpret_cast<const bf16x8*>(bp + 96);
    };
    auto compute = [&](const bf16x8* buf) {
        floatx4 acc0 = {0.f, 0.f, 0.f, 0.f};
        floatx4 acc1 = {0.f, 0.f, 0.f, 0.f};
#pragma unroll
        for (int kc = 0; kc < 4; ++kc) {
            acc0 = __builtin_amdgcn_mfma_f32_16x16x32_bf16(a0[kc], buf[kc], acc0, 0, 0, 0);
            acc1 = __builtin_amdgcn_mfma_f32_16x16x32_bf16(a1[kc], buf[kc], acc1, 0, 0, 0);
        }
#pragma unroll
        for (int r = 0; r < 4; ++r) {
            l0[r] += EXP2F(fmaf(acc0[r], C_EXP, -C_EXP));
            l1[r] += EXP2F(fmaf(acc1[r], C_EXP, -C_EXP));
        }
    };

    // ping-pong register double-buffer over 16 sub-tiles of 16 columns
    bf16x8 bufA[4], bufB[4];
    loadB(bufA, 0);
    for (int it = 0; it < 16; it += 2) {
        loadB(bufB, it + 1);
        compute(bufA);
        loadB(bufA, (it + 2) & 15);   // last one wraps (harmless reload)
        compute(bufB);
    }

    // reduce the 16 columns-per-lane-group, then one atomic per row
    const int i_base = row0 + quad * 4;
#pragma unroll
    for (int r = 0; r < 4; ++r) {
        float s = l0[r];
        s += __shfl_xor(s, 1, 64);
        s += __shfl_xor(s, 2, 64);
        s += __shfl_xor(s, 4, 64);
        s += __shfl_xor(s, 8, 64);
        if (m == 0) atomicAdd(&l_arr[i_base + r], s);
    }
#pragma unroll
    for (int r = 0; r < 4; ++r) {
        float s = l1[r];
        s += __shfl_xor(s, 1, 64);
        s += __shfl_xor(s, 2, 64);
        s += __shfl_xor(s, 4, 64);
        s += __shfl_xor(s, 8, 64);
        if (m == 0) atomicAdd(&l_arr[i_base + 16 + r], s);
    }
}

// ---- kernel 3: per-row logz + picked, block-reduce, last block finalizes --
__global__ void k_aux(const float* __restrict__ emb,
                      const int* __restrict__ labels,
                      const float* __restrict__ l_arr,
                      const unsigned int* __restrict__ nbu,
                      float* __restrict__ accum,
                      unsigned int* __restrict__ counter,
                      float* __restrict__ out) {
    __shared__ float sred[4];
    int wv   = threadIdx.x >> 6;
    int lane = threadIdx.x & 63;
    int i = blockIdx.x * 4 + wv;
    int p = i ^ B_HALF;
    // bf16 self-dot and positive-pair dot (match what the MFMA summed)
    unsigned int ux = nbu[i * 64 + lane], uy = nbu[p * 64 + lane];
    float x0 = __uint_as_float(ux << 16), x1 = __uint_as_float(ux & 0xffff0000u);
    float y0 = __uint_as_float(uy << 16), y1 = __uint_as_float(uy & 0xffff0000u);
    float dii = x0 * x0 + x1 * x1;
    float dip = x0 * y0 + x1 * y1;
    // picked logit in fp32 from raw embeddings
    int a = min(i, p), b = max(i, p);
    int l = labels[i];
    int c = l + (l >= a);
    c += (c >= b);
    const float2* ei = reinterpret_cast<const float2*>(emb + (size_t)i * D);
    const float2* ec = reinterpret_cast<const float2*>(emb + (size_t)c * D);
    float2 xe = ei[lane], ye = ec[lane];
    float dot = xe.x * ye.x + xe.y * ye.y;
    float ssi = xe.x * xe.x + xe.y * xe.y;
    float ssc = ye.x * ye.x + ye.y * ye.y;
#pragma unroll
    for (int off = 32; off >= 1; off >>= 1) {
        dii += __shfl_xor(dii, off, 64);
        dip += __shfl_xor(dip, off, 64);
        dot += __shfl_xor(dot, off, 64);
        ssi += __shfl_xor(ssi, off, 64);
        ssc += __shfl_xor(ssc, off, 64);
    }
    if (lane == 0) {
        float corr = EXP2F(fmaf(dii, C_EXP, -C_EXP)) + EXP2F(fmaf(dip, C_EXP, -C_EXP));
        float lv = l_arr[i] - corr;
        float logz = FIXED_MAX + logf(lv);
        float picked = dot * rsqrtf(ssi) * rsqrtf(ssc) * INV_T;
        sred[wv] = logz - picked;
    }
    __syncthreads();
    if (threadIdx.x == 0) {
        atomicAdd(accum, sred[0] + sred[1] + sred[2] + sred[3]);
        __threadfence();
        unsigned int old = atomicAdd(counter, 1u);
        if (old == gridDim.x - 1) {
            float tot = atomicAdd(accum, 0.0f);  // coherent L2 read
            out[0] = tot * (1.0f / TWO_B);
        }
    }
}

extern "C" void kernel_launch(void* const* d_in, const int* in_sizes, int n_in,
                              void* d_out, int out_size, void* d_ws, size_t ws_size,
                              hipStream_t stream) {
    const float* emb    = (const float*)d_in[0];
    const int*   labels = (const int*)d_in[1];
    char* ws = (char*)d_ws;
    // ws layout: l_arr[8192] f32 | accum f32 + counter u32 (256B pad) | nb bf16
    float*        l_arr   = (float*)ws;
    float*        accum   = (float*)(ws + 32768);
    unsigned int* counter = (unsigned int*)(ws + 32768 + 4);
    __bf16*       nb      = (__bf16*)(ws + 33024);
    float*        out     = (float*)d_out;

    k_normalize<<<TWO_B / 4, 256, 0, stream>>>(emb, nb, l_arr, accum, counter);
    dim3 g2(TWO_B / 128, 32);
    k_simlse<<<g2, 256, 0, stream>>>(nb, l_arr);
    k_aux<<<TWO_B / 4, 256, 0, stream>>>(emb, labels, l_arr,
                                         (const unsigned int*)nb,
                                         accum, counter, out);
}

// Round 4
// 149.346 us; speedup vs baseline: 1.2162x; 1.2162x over previous
//
#include <hip/hip_runtime.h>
#include <hip/hip_bf16.h>

// NT-Xent loss, 2B=8192, D=128, T=0.5. Two dispatches:
//  k_prep : row-normalize -> bf16 nb; picked logit per row in fp32;
//           zero l_arr + counter.
//  k_fused: Gram matrix via MFMA with LDS-staged B (global_load_lds w=16),
//           masked exp-sum (fixed max = 2.0 since cos<=1) -> l_arr atomics;
//           last-finishing block reduces 2+ln(l)-picked and writes out.

typedef __bf16 bf16x8 __attribute__((ext_vector_type(8)));
typedef float floatx4 __attribute__((ext_vector_type(4)));

#define TWO_B 8192
#define B_HALF 4096
#define D 128
#define INV_T 2.0f                 // 1/temperature
#define FIXED_MAX 2.0f             // logit upper bound (cos<=1)
#define C_EXP 2.885390081777927f   // INV_T * log2(e) == FIXED_MAX * log2(e)
#define NSPLIT 16                  // column splits
#define NROWBLK (TWO_B / 128)      // 64 row blocks
#define GRID_TOTAL (NROWBLK * NSPLIT)

#if defined(__has_builtin) && __has_builtin(__builtin_amdgcn_exp2f)
#define EXP2F(x) __builtin_amdgcn_exp2f(x)   // raw v_exp_f32; arg in [-5.8, 0]
#else
#define EXP2F(x) exp2f(x)
#endif
#if defined(__has_builtin) && __has_builtin(__builtin_amdgcn_logf)
#define LOG2F(x) __builtin_amdgcn_logf(x)    // raw v_log_f32 (log2)
#else
#define LOG2F(x) log2f(x)
#endif

__device__ inline void load16_lds(const __bf16* g, __bf16* l) {
    __builtin_amdgcn_global_load_lds(
        (const __attribute__((address_space(1))) unsigned int*)g,
        (__attribute__((address_space(3))) unsigned int*)l, 16, 0, 0);
}

// -------- kernel 1: normalize + picked + zero state ----------------------
__global__ void k_prep(const float* __restrict__ emb,
                       const int* __restrict__ labels,
                       __bf16* __restrict__ nb,
                       float* __restrict__ picked,
                       float* __restrict__ l_arr,
                       unsigned int* __restrict__ counter) {
    int wv   = threadIdx.x >> 6;
    int lane = threadIdx.x & 63;
    int i = blockIdx.x * 4 + wv;
    const float2* e2 = reinterpret_cast<const float2*>(emb + (size_t)i * D);
    float2 v = e2[lane];
    float ssi = v.x * v.x + v.y * v.y;
    // picked column: labels[i] skips cols {i, i^4096}
    int p = i ^ B_HALF;
    int a = min(i, p), b = max(i, p);
    int l = labels[i];
    int c = l + (l >= a);
    c += (c >= b);
    const float2* ec2 = reinterpret_cast<const float2*>(emb + (size_t)c * D);
    float2 u = ec2[lane];
    float dot = v.x * u.x + v.y * u.y;
    float ssc = u.x * u.x + u.y * u.y;
#pragma unroll
    for (int off = 32; off >= 1; off >>= 1) {
        ssi += __shfl_xor(ssi, off, 64);
        dot += __shfl_xor(dot, off, 64);
        ssc += __shfl_xor(ssc, off, 64);
    }
    float rn = rsqrtf(fmaxf(ssi, 1e-16f));
    union { __bf16 h[2]; unsigned int uu; } pk;
    pk.h[0] = (__bf16)(v.x * rn);
    pk.h[1] = (__bf16)(v.y * rn);
    reinterpret_cast<unsigned int*>(nb)[i * 64 + lane] = pk.uu;
    if (lane == 0)
        picked[i] = dot / fmaxf(sqrtf(ssi * ssc), 1e-8f) * INV_T;
    if (blockIdx.x < TWO_B / 256) l_arr[blockIdx.x * 256 + threadIdx.x] = 0.f;
    if (blockIdx.x == 0 && threadIdx.x == 0) counter[0] = 0u;
}

// -------- kernel 2: fused Gram MFMA + masked exp-sum + final reduce ------
// grid (64, 16), block 256 = 4 waves. Block tile: 128 rows x 512 cols.
// B staged in LDS in fragment order via global_load_lds (128-col chunks).
__global__ __launch_bounds__(256, 4) void k_fused(const __bf16* __restrict__ nb,
                                                  float* __restrict__ l_arr,
                                                  const float* __restrict__ picked,
                                                  unsigned int* __restrict__ counter,
                                                  float* __restrict__ out) {
    __shared__ __bf16 lds[16384];            // 32 KB: 128 cols x K=128
    __shared__ float sred[4];
    __shared__ int s_last;

    const int lane = threadIdx.x & 63;
    const int w    = threadIdx.x >> 6;
    const int m    = lane & 15;
    const int quad = lane >> 4;
    const int row0 = blockIdx.x * 128 + w * 32;   // wave rows: row0..row0+31
    const int colB = blockIdx.y * 512;            // block cols: colB..colB+511

    // block-uniform: does this tile contain masked (diag/positive) entries?
    const int r0 = blockIdx.x * 128;
    const int pr0 = r0 ^ B_HALF;
    const bool bmask = ((r0 < colB + 512) && (colB < r0 + 128)) ||
                       ((pr0 < colB + 512) && (colB < pr0 + 128));

    // A fragments: two 16-row tiles, full K=128, in registers (32 VGPR)
    bf16x8 a0[4], a1[4];
#pragma unroll
    for (int kc = 0; kc < 4; ++kc) {
        a0[kc] = *reinterpret_cast<const bf16x8*>(
            nb + (size_t)(row0 + m) * D + kc * 32 + quad * 8);
        a1[kc] = *reinterpret_cast<const bf16x8*>(
            nb + (size_t)(row0 + 16 + m) * D + kc * 32 + quad * 8);
    }

    float l0[4] = {0.f, 0.f, 0.f, 0.f};
    float l1[4] = {0.f, 0.f, 0.f, 0.f};
    const int i0 = row0 + quad * 4;          // l0 rows; l1 rows = i0+16

    for (int ch = 0; ch < 4; ++ch) {
        const int colbase = colB + ch * 128;
        // ---- stage 128 cols x 128 K into LDS, fragment order -----------
        // unit u=(s*4+kc)*64 + quad*16 + m  <->  instr j: s=j, kc=w
        {
            const __bf16* g = nb + (size_t)(colbase + m) * D + w * 32 + quad * 8;
#pragma unroll
            for (int j = 0; j < 8; ++j)
                load16_lds(g + (size_t)j * 16 * D, &lds[j * 2048 + w * 512]);
        }
        __syncthreads();   // compiler drains vmcnt(0) before barrier
        // ---- compute 8 sub-tiles of 16 cols -----------------------------
#pragma unroll
        for (int s = 0; s < 8; ++s) {
            bf16x8 b0 = *reinterpret_cast<const bf16x8*>(&lds[(s * 4 + 0) * 512 + lane * 8]);
            bf16x8 b1 = *reinterpret_cast<const bf16x8*>(&lds[(s * 4 + 1) * 512 + lane * 8]);
            bf16x8 b2 = *reinterpret_cast<const bf16x8*>(&lds[(s * 4 + 2) * 512 + lane * 8]);
            bf16x8 b3 = *reinterpret_cast<const bf16x8*>(&lds[(s * 4 + 3) * 512 + lane * 8]);
            floatx4 acc0 = {0.f, 0.f, 0.f, 0.f};
            floatx4 acc1 = {0.f, 0.f, 0.f, 0.f};
            acc0 = __builtin_amdgcn_mfma_f32_16x16x32_bf16(a0[0], b0, acc0, 0, 0, 0);
            acc1 = __builtin_amdgcn_mfma_f32_16x16x32_bf16(a1[0], b0, acc1, 0, 0, 0);
            acc0 = __builtin_amdgcn_mfma_f32_16x16x32_bf16(a0[1], b1, acc0, 0, 0, 0);
            acc1 = __builtin_amdgcn_mfma_f32_16x16x32_bf16(a1[1], b1, acc1, 0, 0, 0);
            acc0 = __builtin_amdgcn_mfma_f32_16x16x32_bf16(a0[2], b2, acc0, 0, 0, 0);
            acc1 = __builtin_amdgcn_mfma_f32_16x16x32_bf16(a1[2], b2, acc1, 0, 0, 0);
            acc0 = __builtin_amdgcn_mfma_f32_16x16x32_bf16(a0[3], b3, acc0, 0, 0, 0);
            acc1 = __builtin_amdgcn_mfma_f32_16x16x32_bf16(a1[3], b3, acc1, 0, 0, 0);
            const int jj = colbase + s * 16 + m;
            if (bmask) {
#pragma unroll
                for (int r = 0; r < 4; ++r) {
                    float e0 = EXP2F(fmaf(acc0[r], C_EXP, -C_EXP));
                    float e1 = EXP2F(fmaf(acc1[r], C_EXP, -C_EXP));
                    if (((jj ^ (i0 + r)) & ~B_HALF) == 0) e0 = 0.f;
                    if (((jj ^ (i0 + 16 + r)) & ~B_HALF) == 0) e1 = 0.f;
                    l0[r] += e0;
                    l1[r] += e1;
                }
            } else {
#pragma unroll
                for (int r = 0; r < 4; ++r) {
                    l0[r] += EXP2F(fmaf(acc0[r], C_EXP, -C_EXP));
                    l1[r] += EXP2F(fmaf(acc1[r], C_EXP, -C_EXP));
                }
            }
        }
        __syncthreads();   // all waves done reading before next stage
    }

    // ---- per-row column reduction + one atomic per row ------------------
#pragma unroll
    for (int r = 0; r < 4; ++r) {
        float s = l0[r];
        s += __shfl_xor(s, 1, 64);
        s += __shfl_xor(s, 2, 64);
        s += __shfl_xor(s, 4, 64);
        s += __shfl_xor(s, 8, 64);
        if (m == 0) atomicAdd(&l_arr[i0 + r], s);
    }
#pragma unroll
    for (int r = 0; r < 4; ++r) {
        float s = l1[r];
        s += __shfl_xor(s, 1, 64);
        s += __shfl_xor(s, 2, 64);
        s += __shfl_xor(s, 4, 64);
        s += __shfl_xor(s, 8, 64);
        if (m == 0) atomicAdd(&l_arr[i0 + 16 + r], s);
    }

    // ---- last-finishing block reduces the loss --------------------------
    __threadfence();
    if (threadIdx.x == 0) {
        unsigned int old = atomicAdd(counter, 1u);
        s_last = (old == GRID_TOTAL - 1);
    }
    __syncthreads();
    if (s_last) {
        float s = 0.f;
#pragma unroll
        for (int k = 0; k < TWO_B / 256; ++k) {
            int i = threadIdx.x + k * 256;
            float lv = __hip_atomic_load(&l_arr[i], __ATOMIC_RELAXED,
                                         __HIP_MEMORY_SCOPE_AGENT);
            s += FIXED_MAX + LOG2F(lv) * 0.6931471805599453f - picked[i];
        }
#pragma unroll
        for (int off = 32; off >= 1; off >>= 1) s += __shfl_xor(s, off, 64);
        if ((threadIdx.x & 63) == 0) sred[threadIdx.x >> 6] = s;
        __syncthreads();
        if (threadIdx.x == 0)
            out[0] = (sred[0] + sred[1] + sred[2] + sred[3]) * (1.0f / TWO_B);
    }
}

extern "C" void kernel_launch(void* const* d_in, const int* in_sizes, int n_in,
                              void* d_out, int out_size, void* d_ws, size_t ws_size,
                              hipStream_t stream) {
    const float* emb    = (const float*)d_in[0];
    const int*   labels = (const int*)d_in[1];
    char* ws = (char*)d_ws;
    // ws layout: l_arr[8192] f32 | picked[8192] f32 | counter | nb bf16[8192*128]
    float*        l_arr   = (float*)ws;
    float*        picked  = (float*)(ws + 32768);
    unsigned int* counter = (unsigned int*)(ws + 65536);
    __bf16*       nb      = (__bf16*)(ws + 65792);
    float*        out     = (float*)d_out;

    k_prep<<<TWO_B / 4, 256, 0, stream>>>(emb, labels, nb, picked, l_arr, counter);
    dim3 g2(NROWBLK, NSPLIT);
    k_fused<<<g2, 256, 0, stream>>>(nb, l_arr, picked, counter, out);
}